// Round 1
// baseline (552.800 us; speedup 1.0000x reference)
//
#include <hip/hip_runtime.h>
#include <cstddef>
#include <cstdint>

#define EPSBN 1e-5f
constexpr int B_ = 4, N_ = 2048, K_ = 20;

typedef __attribute__((ext_vector_type(8))) _Float16 half8v;
typedef __attribute__((ext_vector_type(4))) float f32x4;
typedef const __attribute__((address_space(1))) unsigned int* gas_t;
typedef __attribute__((address_space(3))) unsigned int* las_t;

// batch-XCD swizzle: block B -> (batch, local) with B&7 = XCD slot, batch b on slots {2b,2b+1}
__device__ __forceinline__ void swz_batch(int B, int& b, int& local) {
    b = (B & 7) >> 1;
    local = ((B >> 3) << 1) | (B & 1);
}

// device-coherent load (cross-XCD visible) for reading atomic partials
__device__ __forceinline__ float agent_load(const float* p) {
    return __hip_atomic_load(p, __ATOMIC_RELAXED, __HIP_MEMORY_SCOPE_AGENT);
}

// last-block finalize: sum 64 slices -> scale/shift (replaces k_finalize_sl kernel)
__device__ __forceinline__ void finalize_tail(const float* __restrict__ psum,
                                              const float* __restrict__ psq,
                                              const float* __restrict__ g,
                                              const float* __restrict__ b,
                                              float cntInv, int O, int nblk,
                                              float* __restrict__ scale,
                                              float* __restrict__ shift,
                                              int* __restrict__ cnt) {
    __shared__ int s_last;
    __threadfence();            // each thread: its stat atomics are device-visible
    __syncthreads();            // whole block done fencing
    if (threadIdx.x == 0) s_last = (atomicAdd(cnt, 1) == nblk - 1);
    __syncthreads();
    if (!s_last) return;
    for (int o = threadIdx.x; o < O; o += 256) {
        float s = 0.f, q = 0.f;
#pragma unroll 8
        for (int i = 0; i < 64; ++i) {
            s += agent_load(&psum[i * 1024 + o]);
            q += agent_load(&psq[i * 1024 + o]);
        }
        float m = s * cntInv;
        float v = q * cntInv - m * m;
        float sc = g[o] * rsqrtf(fmaxf(v, 0.f) + EPSBN);
        scale[o] = sc;
        shift[o] = b[o] - m * sc;
    }
}

// ---------------- fused weight prep (layers 1-3 conv + w4 cast) ----------------

__device__ __forceinline__ void prep_conv(const float* __restrict__ W, _Float16* __restrict__ W2h,
                                          int O, int C, int i) {
    int o = i / C, c = i - o * C;
    float a = W[o * 2 * C + c];
    float d = W[o * 2 * C + C + c] - a;
    W2h[(size_t)o * C + c] = (_Float16)a;
    W2h[(size_t)(O + o) * C + c] = (_Float16)d;
}

__global__ void k_prep_all(const float* __restrict__ w1, const float* __restrict__ w2,
                           const float* __restrict__ w3, const float* __restrict__ w4,
                           _Float16* __restrict__ W2h1, _Float16* __restrict__ W2h2,
                           _Float16* __restrict__ W2h3, _Float16* __restrict__ w4h) {
    int i = blockIdx.x * 256 + threadIdx.x;
    if (i < 8192) { prep_conv(w1, W2h1, 128, 64, i); return; }
    i -= 8192;
    if (i < 32768) { prep_conv(w2, W2h2, 256, 128, i); return; }
    i -= 32768;
    if (i < 131072) { prep_conv(w3, W2h3, 512, 256, i); return; }
    i -= 131072;
    if (i < 983040) w4h[i] = (_Float16)w4[i];
}

// ---------------- generic MFMA GEMM: out(fp16) = A (8192 x K, stride sa) @ Bw^T ----------------
// 128x128 tile, 4 waves x (64x64), global_load_lds staging with XOR-swizzled LDS.
// 3 blocks/CU for latency hiding (32KB LDS each).
template<bool STATS>
__global__ __launch_bounds__(256, 3)
void k_gemm(const _Float16* __restrict__ A, int sa,
            const _Float16* __restrict__ Bw, int K,
            _Float16* __restrict__ outp, int so,
            float* __restrict__ psum, float* __restrict__ psq,
            const float* __restrict__ gvec, const float* __restrict__ bvec,
            float* __restrict__ scale, float* __restrict__ shift, int* __restrict__ cnt) {
    __shared__ __align__(16) _Float16 Als[128 * 64];
    __shared__ __align__(16) _Float16 Bls[128 * 64];
    const int tid = threadIdx.x, lane = tid & 63, w = tid >> 6;
    int bsw, lsw;
    swz_batch(blockIdx.x, bsw, lsw);                 // lsw in [0,16)
    const int m0 = (bsw * 16 + lsw) * 128;
    const int n0 = blockIdx.y * 128;
    const int wr = (w >> 1) * 64, wc = (w & 1) * 64;

    f32x4 acc[4][4];
#pragma unroll
    for (int i = 0; i < 4; ++i)
#pragma unroll
        for (int j = 0; j < 4; ++j) acc[i][j] = (f32x4){0.f, 0.f, 0.f, 0.f};

    int srow[4], scol[4];
#pragma unroll
    for (int j = 0; j < 4; ++j) {
        int idx = w * 256 + j * 64 + lane;
        srow[j] = idx >> 3;
        scol[j] = ((idx & 7) ^ (srow[j] & 7)) * 8;
    }
    int aoff[4][2], boff[4][2];
#pragma unroll
    for (int i = 0; i < 4; ++i) {
        int ra = wr + i * 16 + (lane & 15);
        int rb = wc + i * 16 + (lane & 15);
#pragma unroll
        for (int t = 0; t < 2; ++t) {
            aoff[i][t] = ra * 64 + ((((lane >> 4) + t * 4) ^ (ra & 7)) * 8);
            boff[i][t] = rb * 64 + ((((lane >> 4) + t * 4) ^ (rb & 7)) * 8);
        }
    }

    for (int c0 = 0; c0 < K; c0 += 64) {
#pragma unroll
        for (int j = 0; j < 4; ++j) {
            const _Float16* ga = &A[(size_t)(m0 + srow[j]) * sa + c0 + scol[j]];
            const _Float16* gb = &Bw[(size_t)(n0 + srow[j]) * K + c0 + scol[j]];
            __builtin_amdgcn_global_load_lds((gas_t)(const void*)ga,
                                             (las_t)(void*)&Als[(w * 256 + j * 64) * 8], 16, 0, 0);
            __builtin_amdgcn_global_load_lds((gas_t)(const void*)gb,
                                             (las_t)(void*)&Bls[(w * 256 + j * 64) * 8], 16, 0, 0);
        }
        __syncthreads();
#pragma unroll
        for (int t = 0; t < 2; ++t) {
            half8v a[4], b[4];
#pragma unroll
            for (int i = 0; i < 4; ++i) {
                a[i] = *(const half8v*)&Als[aoff[i][t]];
                b[i] = *(const half8v*)&Bls[boff[i][t]];
            }
#pragma unroll
            for (int i = 0; i < 4; ++i)
#pragma unroll
                for (int j = 0; j < 4; ++j)
                    acc[i][j] = __builtin_amdgcn_mfma_f32_16x16x32_f16(a[i], b[j], acc[i][j], 0, 0, 0);
        }
        __syncthreads();
    }
#pragma unroll
    for (int i = 0; i < 4; ++i)
#pragma unroll
        for (int j = 0; j < 4; ++j)
#pragma unroll
            for (int e = 0; e < 4; ++e) {
                int row = m0 + wr + i * 16 + (lane >> 4) * 4 + e;
                int col = n0 + wc + j * 16 + (lane & 15);
                outp[(size_t)row * so + col] = (_Float16)acc[i][j][e];
            }
    if constexpr (STATS) {
        int slice = blockIdx.x & 63;
#pragma unroll
        for (int j = 0; j < 4; ++j) {
            float s = 0.f, q = 0.f;
#pragma unroll
            for (int i = 0; i < 4; ++i)
#pragma unroll
                for (int e = 0; e < 4; ++e) {
                    float v = acc[i][j][e];
                    s += v; q += v * v;
                }
            s += __shfl_xor(s, 16); s += __shfl_xor(s, 32);
            q += __shfl_xor(q, 16); q += __shfl_xor(q, 32);
            if ((lane >> 4) == 0) {
                int col = n0 + wc + j * 16 + lane;
                atomicAdd(&psum[slice * 1024 + col], s);
                atomicAdd(&psq[slice * 1024 + col], q);
            }
        }
        finalize_tail(psum, psq, gvec, bvec, 1.f / (B_ * N_), 1024,
                      (int)(gridDim.x * gridDim.y), scale, shift, cnt);
    }
}

// ---------------- layer-0: fused dense (C=3) + gather-reduce + BN stats + finalize ----------------
__global__ __launch_bounds__(256)
void k_gather0(const float* __restrict__ x, const float* __restrict__ w0,
               const int* __restrict__ nidx, const float* __restrict__ g,
               const float* __restrict__ bvec,
               _Float16* __restrict__ exth,
               float* __restrict__ psum, float* __restrict__ psq,
               float* __restrict__ scale, float* __restrict__ shift, int* __restrict__ cnt) {
    constexpr int O = 64, VPT = 8, P = 32;
    __shared__ float s_red[P * O];
    __shared__ float q_red[P * O];
    const int tid = threadIdx.x;
    const int pl = tid / VPT, v = tid % VPT;
    int bsw, local;
    swz_batch(blockIdx.x, bsw, local);               // grid 256: local in [0,32)
    const int bbase = bsw * N_;
    const int p = bbase + local * P + pl;
    // per-thread weights for channels v*8 .. v*8+7 (static-indexed -> registers)
    float wa[8][3], wd[8][3], sg[8];
#pragma unroll
    for (int e = 0; e < 8; ++e) {
        int o = v * 8 + e;
        float a0 = w0[o * 6], a1 = w0[o * 6 + 1], a2 = w0[o * 6 + 2];
        wa[e][0] = a0; wa[e][1] = a1; wa[e][2] = a2;
        wd[e][0] = w0[o * 6 + 3] - a0;
        wd[e][1] = w0[o * 6 + 4] - a1;
        wd[e][2] = w0[o * 6 + 5] - a2;
        sg[e] = (g[o] >= 0.f) ? 1.f : -1.f;
    }
    float mx[8], sm[8], sq[8];
#pragma unroll
    for (int e = 0; e < 8; ++e) { mx[e] = -3.4e38f; sm[e] = 0.f; sq[e] = 0.f; }
    const int* np = nidx + p * K_;
#pragma unroll 4
    for (int k = 0; k < K_; ++k) {
        int j = bbase + np[k];
        float x0 = x[j * 3], x1 = x[j * 3 + 1], x2 = x[j * 3 + 2];
#pragma unroll
        for (int e = 0; e < 8; ++e) {
            float f = wa[e][0] * x0 + wa[e][1] * x1 + wa[e][2] * x2;
            mx[e] = fmaxf(mx[e], f * sg[e]);
            sm[e] += f;
            sq[e] += f * f;
        }
    }
    float xp0 = x[p * 3], xp1 = x[p * 3 + 1], xp2 = x[p * 3 + 2];
    const float Kf = (float)K_;
    half8v exo;
#pragma unroll
    for (int e = 0; e < 8; ++e) {
        float zf = wd[e][0] * xp0 + wd[e][1] * xp1 + wd[e][2] * xp2;
        exo[e] = (_Float16)(sg[e] * mx[e] + zf);
        s_red[pl * O + v * 8 + e] = sm[e] + Kf * zf;
        q_red[pl * O + v * 8 + e] = sq[e] + 2.f * zf * sm[e] + Kf * zf * zf;
    }
    *(half8v*)&exth[(size_t)p * O + v * 8] = exo;
    __syncthreads();
    int slice = blockIdx.x & 63;
    for (int ch = tid; ch < O; ch += 256) {
        float s = 0.f, q = 0.f;
#pragma unroll
        for (int pp = 0; pp < P; ++pp) { s += s_red[pp * O + ch]; q += q_red[pp * O + ch]; }
        atomicAdd(&psum[slice * 1024 + ch], s);
        atomicAdd(&psq[slice * 1024 + ch], q);
    }
    finalize_tail(psum, psq, g, bvec, 1.f / (B_ * N_ * K_), O, (int)gridDim.x,
                  scale, shift, cnt);
}

// ---------------- gather-reduce + fused BN stats + finalize (batch-XCD-swizzled) ----------------
template<int O>
__global__ __launch_bounds__(256)
void k_gather(const _Float16* __restrict__ Z, const int* __restrict__ nidx,
              const float* __restrict__ g, const float* __restrict__ bvec,
              _Float16* __restrict__ exth,
              float* __restrict__ psum, float* __restrict__ psq,
              float* __restrict__ scale, float* __restrict__ shift, int* __restrict__ cnt) {
    constexpr int VPT = O / 8, P = 256 / VPT;
    __shared__ float s_red[P * O];
    __shared__ float q_red[P * O];
    const int tid = threadIdx.x;
    const int pl = tid / VPT, v = tid % VPT;
    int bsw, local;
    swz_batch(blockIdx.x, bsw, local);               // local in [0, 2048/P)
    const int bbase = bsw * N_;
    const int p = bbase + local * P + pl;
    float sg[8];
#pragma unroll
    for (int e = 0; e < 8; ++e) sg[e] = (g[v * 8 + e] >= 0.f) ? 1.f : -1.f;
    float mx[8], sm[8], sq[8];
#pragma unroll
    for (int e = 0; e < 8; ++e) { mx[e] = -3.4e38f; sm[e] = 0.f; sq[e] = 0.f; }
    const int* np = nidx + p * K_;
#pragma unroll 4
    for (int k = 0; k < K_; ++k) {
        int j = np[k];
        half8v z = *(const half8v*)&Z[(size_t)(bbase + j) * (2 * O) + v * 8];
#pragma unroll
        for (int e = 0; e < 8; ++e) {
            float f = (float)z[e];
            mx[e] = fmaxf(mx[e], f * sg[e]);
            sm[e] += f;
            sq[e] += f * f;
        }
    }
    half8v zd = *(const half8v*)&Z[(size_t)p * (2 * O) + O + v * 8];
    const float Kf = (float)K_;
    half8v exo;
#pragma unroll
    for (int e = 0; e < 8; ++e) {
        float zf = (float)zd[e];
        exo[e] = (_Float16)(sg[e] * mx[e] + zf);
        s_red[pl * O + v * 8 + e] = sm[e] + Kf * zf;
        q_red[pl * O + v * 8 + e] = sq[e] + 2.f * zf * sm[e] + Kf * zf * zf;
    }
    *(half8v*)&exth[(size_t)p * O + v * 8] = exo;
    __syncthreads();
    int slice = blockIdx.x & 63;
    for (int ch = tid; ch < O; ch += 256) {
        float s = 0.f, q = 0.f;
#pragma unroll
        for (int pp = 0; pp < P; ++pp) { s += s_red[pp * O + ch]; q += q_red[pp * O + ch]; }
        atomicAdd(&psum[slice * 1024 + ch], s);
        atomicAdd(&psq[slice * 1024 + ch], q);
    }
    finalize_tail(psum, psq, g, bvec, 1.f / (B_ * N_ * K_), O, (int)gridDim.x,
                  scale, shift, cnt);
}

// BN + lrelu on selected extremum (fp16 in) -> fp16 cat slice; batch-XCD-swizzled
template<int O>
__global__ void k_bn_apply(const _Float16* __restrict__ exth,
                           const float* __restrict__ scale, const float* __restrict__ shift,
                           _Float16* __restrict__ cath, int coff) {
    constexpr int PPB = 2048 / O;                    // points per block (256 thr x 8 elems)
    int bsw, local;
    swz_batch(blockIdx.x, bsw, local);
    const int pt_base = bsw * N_ + local * PPB;
    int tid = threadIdx.x;
    int pt = pt_base + (tid * 8) / O;
    int v8 = (tid * 8) & (O - 1);
    half8v hx = *(const half8v*)&exth[(size_t)pt * O + v8];
    half8v r;
#pragma unroll
    for (int e = 0; e < 8; ++e) {
        int o = v8 + e;
        float y = scale[o] * (float)hx[e] + shift[o];
        y = y > 0.f ? y : 0.2f * y;
        r[e] = (_Float16)y;
    }
    *(half8v*)&cath[(size_t)pt * 960 + coff + v8] = r;
}

// BN+lrelu on Y4 (B,N,1024 fp16), transposed store -> fo (B,1024,N f32), fused pool partials
__global__ void k_feats_out(const _Float16* __restrict__ Y4, const float* __restrict__ scale,
                            const float* __restrict__ shift, float* __restrict__ fo,
                            float* __restrict__ pmax, float* __restrict__ psumn) {
    __shared__ float tile[32][33];
    int tx = threadIdx.x, ty = threadIdx.y;      // (32,8)
    int b = blockIdx.z;
    int n0 = blockIdx.x * 32, c0 = blockIdx.y * 32;
#pragma unroll
    for (int i = 0; i < 4; ++i) {
        int n = n0 + ty + i * 8;
        int c = c0 + tx;
        float v = (float)Y4[((size_t)(b * N_ + n)) * 1024 + c];
        v = scale[c] * v + shift[c];
        v = v > 0.f ? v : 0.2f * v;
        tile[ty + i * 8][tx] = v;
    }
    __syncthreads();
#pragma unroll
    for (int i = 0; i < 4; ++i) {
        int c = c0 + ty + i * 8;
        int n = n0 + tx;
        float v2 = tile[tx][ty + i * 8];
        fo[((size_t)(b * 1024 + c)) * N_ + n] = v2;
        float mx = v2, s = v2;
#pragma unroll
        for (int d = 1; d < 32; d <<= 1) {
            mx = fmaxf(mx, __shfl_xor(mx, d));
            s += __shfl_xor(s, d);
        }
        if (tx == 0) {
            int bc = (b << 10) + c;
            pmax[(size_t)bc * 64 + blockIdx.x] = mx;
            psumn[(size_t)bc * 64 + blockIdx.x] = s;
        }
    }
}

// final pool: per (b,c) reduce 64 tile-partials -> z0 (B,2048) = [max | mean]
__global__ void k_pool2(const float* __restrict__ pmax, const float* __restrict__ psumn,
                        float* __restrict__ z0) {
    int bc = blockIdx.x * 4 + (threadIdx.x >> 6);
    int lane = threadIdx.x & 63;
    float mx = pmax[(size_t)bc * 64 + lane];
    float s  = psumn[(size_t)bc * 64 + lane];
#pragma unroll
    for (int d = 1; d < 64; d <<= 1) {
        mx = fmaxf(mx, __shfl_xor(mx, d));
        s += __shfl_xor(s, d);
    }
    if (lane == 0) {
        int b = bc >> 10, c = bc & 1023;
        z0[b * 2048 + c] = mx;
        z0[b * 2048 + 1024 + c] = s * (1.f / N_);
    }
}

// ---------------- FC: one wave per (batch, output) dot product; optional fused batch-BN+lrelu ----------------
// gg!=null: zout[b][o] = lrelu(bn_over_batch(zin@W^T + bias)) ; else plain +bias.
__global__ void k_fc(const float* __restrict__ zin, const float* __restrict__ W,
                     const float* __restrict__ bias,
                     const float* __restrict__ gg, const float* __restrict__ gb,
                     int C, int O, float* __restrict__ zout) {
    __shared__ float sh4[4];
    const int b = threadIdx.x >> 6;
    const int lane = threadIdx.x & 63;
    const int o = blockIdx.x;
    const float* wr = W + (size_t)o * C;
    const float* zr = zin + b * C;
    float s = 0.f;
    for (int c = lane * 4; c < C; c += 256) {
        const float4 wv = *(const float4*)&wr[c];
        const float4 zv = *(const float4*)&zr[c];
        s += wv.x * zv.x + wv.y * zv.y + wv.z * zv.z + wv.w * zv.w;
    }
    s += __shfl_xor(s, 1);
    s += __shfl_xor(s, 2);
    s += __shfl_xor(s, 4);
    s += __shfl_xor(s, 8);
    s += __shfl_xor(s, 16);
    s += __shfl_xor(s, 32);
    if (!gg) {
        if (lane == 0) zout[b * O + o] = s + (bias ? bias[o] : 0.f);
        return;
    }
    if (lane == 0) sh4[b] = s + (bias ? bias[o] : 0.f);
    __syncthreads();
    if (threadIdx.x == 0) {
        float v0 = sh4[0], v1 = sh4[1], v2 = sh4[2], v3 = sh4[3];
        float m = 0.25f * (v0 + v1 + v2 + v3);
        float d0 = v0 - m, d1 = v1 - m, d2 = v2 - m, d3 = v3 - m;
        float var = 0.25f * (d0 * d0 + d1 * d1 + d2 * d2 + d3 * d3);
        float sc = gg[o] * rsqrtf(var + EPSBN);
        float shv = gb[o];
        float r0 = sc * d0 + shv, r1 = sc * d1 + shv, r2 = sc * d2 + shv, r3 = sc * d3 + shv;
        zout[o]         = r0 > 0.f ? r0 : 0.2f * r0;
        zout[O + o]     = r1 > 0.f ? r1 : 0.2f * r1;
        zout[2 * O + o] = r2 > 0.f ? r2 : 0.2f * r2;
        zout[3 * O + o] = r3 > 0.f ? r3 : 0.2f * r3;
    }
}

// ---------------- launch ----------------

extern "C" void kernel_launch(void* const* d_in, const int* in_sizes, int n_in,
                              void* d_out, int out_size, void* d_ws, size_t ws_size,
                              hipStream_t stream) {
    const float* x    = (const float*)d_in[0];
    const int*   nidx = (const int*)d_in[1];
    const float* w[5]  = {(const float*)d_in[2], (const float*)d_in[5], (const float*)d_in[8],
                          (const float*)d_in[11], (const float*)d_in[14]};
    const float* g[5]  = {(const float*)d_in[3], (const float*)d_in[6], (const float*)d_in[9],
                          (const float*)d_in[12], (const float*)d_in[15]};
    const float* bb[5] = {(const float*)d_in[4], (const float*)d_in[7], (const float*)d_in[10],
                          (const float*)d_in[13], (const float*)d_in[16]};
    const float* lw1 = (const float*)d_in[17];
    const float* g6  = (const float*)d_in[18];
    const float* b6  = (const float*)d_in[19];
    const float* lw2 = (const float*)d_in[20];
    const float* lb2 = (const float*)d_in[21];
    const float* g7  = (const float*)d_in[22];
    const float* b7  = (const float*)d_in[23];
    const float* lw3 = (const float*)d_in[24];
    const float* lb3 = (const float*)d_in[25];

    float* out = (float*)d_out;
    float* fo  = out + 1024;              // feats (B,1024,N)

    uint8_t* base8 = (uint8_t*)d_ws;
    size_t off = 0;
    auto alloc = [&](size_t bytes) -> void* {
        void* r = base8 + off;
        off += (bytes + 255) & ~(size_t)255;
        return r;
    };
    _Float16* cath = (_Float16*)alloc((size_t)B_ * N_ * 960 * 2);   // 15.7 MB
    _Float16* Z    = (_Float16*)alloc((size_t)8192 * 1024 * 2);     // 16.8 MB
    _Float16* exth = (_Float16*)alloc((size_t)8192 * 512 * 2);      // 8.4 MB
    _Float16* Y4   = (_Float16*)alloc((size_t)8192 * 1024 * 2);     // 16.8 MB
    _Float16* W2h1 = (_Float16*)alloc((size_t)256 * 64 * 2);
    _Float16* W2h2 = (_Float16*)alloc((size_t)512 * 128 * 2);
    _Float16* W2h3 = (_Float16*)alloc((size_t)1024 * 256 * 2);
    _Float16* w4h  = (_Float16*)alloc((size_t)1024 * 960 * 2);
    float* psumall = (float*)alloc((size_t)5 * 131072 * 4);         // 2.6 MB, 5 regions
    int*   cnts    = (int*)alloc(256);                              // 5 block-completion counters
    float* pmax  = (float*)alloc((size_t)4096 * 64 * 4);            // 1 MB
    float* psumn = (float*)alloc((size_t)4096 * 64 * 4);            // 1 MB
    float* scalev= (float*)alloc(1024 * 4);
    float* shiftv= (float*)alloc(1024 * 4);
    float* z0    = (float*)alloc(8192 * 4);
    float* z1    = (float*)alloc(4096 * 4);
    float* z2    = (float*)alloc(2048 * 4);
    (void)ws_size; (void)in_sizes; (void)n_in; (void)out_size;

    auto psumR = [&](int r) { return psumall + (size_t)r * 131072; };
    auto psqR  = [&](int r) { return psumall + (size_t)r * 131072 + 65536; };

    // one upfront zero of all stat regions + counters, one fused weight-prep launch
    hipMemsetAsync(psumall, 0, (size_t)5 * 131072 * 4 + 256, stream);
    k_prep_all<<<(8192 + 32768 + 131072 + 983040 + 255) / 256, 256, 0, stream>>>(
        w[1], w[2], w[3], w[4], W2h1, W2h2, W2h3, w4h);

    // ---- layer 0 (C=3 -> O=64): fused dense + gather + stats + finalize ----
    k_gather0<<<256, 256, 0, stream>>>(x, w[0], nidx, g[0], bb[0], exth,
                                       psumR(0), psqR(0), scalev, shiftv, cnts + 0);
    k_bn_apply<64><<<256, 256, 0, stream>>>(exth, scalev, shiftv, cath, 0);

    // ---- layers 1-3: dense MFMA GEMM + fused gather(+finalize) ----
    struct LayerCfg { int coff_in, C, O, coff_out, li; const _Float16* Wh; };
    const LayerCfg L[3] = {
        { 0,   64,  128, 64,  1, W2h1 },
        { 64,  128, 256, 192, 2, W2h2 },
        { 192, 256, 512, 448, 3, W2h3 },
    };
    for (int i = 0; i < 3; ++i) {
        const LayerCfg& Lc = L[i];
        dim3 ggrid(64, (2 * Lc.O) / 128);
        k_gemm<false><<<ggrid, 256, 0, stream>>>(cath + Lc.coff_in, 960, Lc.Wh, Lc.C,
                                                 Z, 2 * Lc.O, nullptr, nullptr,
                                                 nullptr, nullptr, nullptr, nullptr, nullptr);
        if (Lc.O == 128) {
            k_gather<128><<<512, 256, 0, stream>>>(Z, nidx, g[Lc.li], bb[Lc.li], exth,
                                                   psumR(i + 1), psqR(i + 1),
                                                   scalev, shiftv, cnts + i + 1);
            k_bn_apply<128><<<512, 256, 0, stream>>>(exth, scalev, shiftv, cath, Lc.coff_out);
        } else if (Lc.O == 256) {
            k_gather<256><<<1024, 256, 0, stream>>>(Z, nidx, g[Lc.li], bb[Lc.li], exth,
                                                    psumR(i + 1), psqR(i + 1),
                                                    scalev, shiftv, cnts + i + 1);
            k_bn_apply<256><<<1024, 256, 0, stream>>>(exth, scalev, shiftv, cath, Lc.coff_out);
        } else {
            k_gather<512><<<2048, 256, 0, stream>>>(Z, nidx, g[Lc.li], bb[Lc.li], exth,
                                                    psumR(i + 1), psqR(i + 1),
                                                    scalev, shiftv, cnts + i + 1);
            k_bn_apply<512><<<2048, 256, 0, stream>>>(exth, scalev, shiftv, cath, Lc.coff_out);
        }
    }

    // ---- feats = lrelu(bn(w4 @ cat)) with fused column stats + finalize ----
    k_gemm<true><<<dim3(64, 8), 256, 0, stream>>>(cath, 960, w4h, 960, Y4, 1024,
                                                  psumR(4), psqR(4), g[4], bb[4],
                                                  scalev, shiftv, cnts + 4);
    k_feats_out<<<dim3(64, 32, 4), dim3(32, 8), 0, stream>>>(Y4, scalev, shiftv, fo, pmax, psumn);
    k_pool2<<<1024, 256, 0, stream>>>(pmax, psumn, z0);

    // ---- FC head (BN fused into FC blocks) ----
    k_fc<<<1024, 256, 0, stream>>>(z0, lw1, nullptr, g6, b6, 2048, 1024, z1);
    k_fc<<<512, 256, 0, stream>>>(z1, lw2, lb2, g7, b7, 1024, 512, z2);
    k_fc<<<256, 256, 0, stream>>>(z2, lw3, lb3, nullptr, nullptr, 512, 256, out);
}

// Round 2
// 216.350 us; speedup vs baseline: 2.5551x; 2.5551x over previous
//
#include <hip/hip_runtime.h>
#include <cstddef>
#include <cstdint>

#define EPSBN 1e-5f
constexpr int B_ = 4, N_ = 2048, K_ = 20;

typedef __attribute__((ext_vector_type(8))) _Float16 half8v;
typedef __attribute__((ext_vector_type(4))) float f32x4;
typedef const __attribute__((address_space(1))) unsigned int* gas_t;
typedef __attribute__((address_space(3))) unsigned int* las_t;

// batch-XCD swizzle: block B -> (batch, local) with B&7 = XCD slot, batch b on slots {2b,2b+1}
__device__ __forceinline__ void swz_batch(int B, int& b, int& local) {
    b = (B & 7) >> 1;
    local = ((B >> 3) << 1) | (B & 1);
}

// device-coherent load (cross-XCD visible) for reading atomic partials
__device__ __forceinline__ float agent_load(const float* p) {
    return __hip_atomic_load(p, __ATOMIC_RELAXED, __HIP_MEMORY_SCOPE_AGENT);
}

// last-block finalize: sum 64 slices -> scale/shift (replaces a separate kernel).
// NO __threadfence here (round-1 lesson: device fence = L2 writeback per wave, ~200us!).
// Ordering without it: stat partials are device-scope atomicAdds (coherent-point ops);
// __syncthreads() compiles with s_waitcnt vmcnt(0) before s_barrier, so all this block's
// atomics are COMPLETE at the coherent point before thread 0 signals the counter (also a
// device-scope atomic). Observing cnt==nblk-1 therefore implies all partials are visible;
// the last block reads them with agent-scope (L1-bypassing) atomic loads.
__device__ __forceinline__ void finalize_tail(const float* __restrict__ psum,
                                              const float* __restrict__ psq,
                                              const float* __restrict__ g,
                                              const float* __restrict__ b,
                                              float cntInv, int O, int nblk,
                                              float* __restrict__ scale,
                                              float* __restrict__ shift,
                                              int* __restrict__ cnt) {
    __shared__ int s_last;
    __syncthreads();            // drains vmcnt: this block's stat atomics are complete
    if (threadIdx.x == 0) s_last = (atomicAdd(cnt, 1) == nblk - 1);
    __syncthreads();
    if (!s_last) return;
    for (int o = threadIdx.x; o < O; o += 256) {
        float s = 0.f, q = 0.f;
#pragma unroll 8
        for (int i = 0; i < 64; ++i) {
            s += agent_load(&psum[i * 1024 + o]);
            q += agent_load(&psq[i * 1024 + o]);
        }
        float m = s * cntInv;
        float v = q * cntInv - m * m;
        float sc = g[o] * rsqrtf(fmaxf(v, 0.f) + EPSBN);
        scale[o] = sc;
        shift[o] = b[o] - m * sc;
    }
}

// ---------------- fused weight prep (layers 1-3 conv + w4 cast) ----------------

__device__ __forceinline__ void prep_conv(const float* __restrict__ W, _Float16* __restrict__ W2h,
                                          int O, int C, int i) {
    int o = i / C, c = i - o * C;
    float a = W[o * 2 * C + c];
    float d = W[o * 2 * C + C + c] - a;
    W2h[(size_t)o * C + c] = (_Float16)a;
    W2h[(size_t)(O + o) * C + c] = (_Float16)d;
}

__global__ void k_prep_all(const float* __restrict__ w1, const float* __restrict__ w2,
                           const float* __restrict__ w3, const float* __restrict__ w4,
                           _Float16* __restrict__ W2h1, _Float16* __restrict__ W2h2,
                           _Float16* __restrict__ W2h3, _Float16* __restrict__ w4h) {
    int i = blockIdx.x * 256 + threadIdx.x;
    if (i < 8192) { prep_conv(w1, W2h1, 128, 64, i); return; }
    i -= 8192;
    if (i < 32768) { prep_conv(w2, W2h2, 256, 128, i); return; }
    i -= 32768;
    if (i < 131072) { prep_conv(w3, W2h3, 512, 256, i); return; }
    i -= 131072;
    if (i < 983040) w4h[i] = (_Float16)w4[i];
}

// ---------------- generic MFMA GEMM: out(fp16) = A (8192 x K, stride sa) @ Bw^T ----------------
// 128x128 tile, 4 waves x (64x64), global_load_lds staging with XOR-swizzled LDS.
// 3 blocks/CU for latency hiding (32KB LDS each).
template<bool STATS>
__global__ __launch_bounds__(256, 3)
void k_gemm(const _Float16* __restrict__ A, int sa,
            const _Float16* __restrict__ Bw, int K,
            _Float16* __restrict__ outp, int so,
            float* __restrict__ psum, float* __restrict__ psq,
            const float* __restrict__ gvec, const float* __restrict__ bvec,
            float* __restrict__ scale, float* __restrict__ shift, int* __restrict__ cnt) {
    __shared__ __align__(16) _Float16 Als[128 * 64];
    __shared__ __align__(16) _Float16 Bls[128 * 64];
    const int tid = threadIdx.x, lane = tid & 63, w = tid >> 6;
    int bsw, lsw;
    swz_batch(blockIdx.x, bsw, lsw);                 // lsw in [0,16)
    const int m0 = (bsw * 16 + lsw) * 128;
    const int n0 = blockIdx.y * 128;
    const int wr = (w >> 1) * 64, wc = (w & 1) * 64;

    f32x4 acc[4][4];
#pragma unroll
    for (int i = 0; i < 4; ++i)
#pragma unroll
        for (int j = 0; j < 4; ++j) acc[i][j] = (f32x4){0.f, 0.f, 0.f, 0.f};

    int srow[4], scol[4];
#pragma unroll
    for (int j = 0; j < 4; ++j) {
        int idx = w * 256 + j * 64 + lane;
        srow[j] = idx >> 3;
        scol[j] = ((idx & 7) ^ (srow[j] & 7)) * 8;
    }
    int aoff[4][2], boff[4][2];
#pragma unroll
    for (int i = 0; i < 4; ++i) {
        int ra = wr + i * 16 + (lane & 15);
        int rb = wc + i * 16 + (lane & 15);
#pragma unroll
        for (int t = 0; t < 2; ++t) {
            aoff[i][t] = ra * 64 + ((((lane >> 4) + t * 4) ^ (ra & 7)) * 8);
            boff[i][t] = rb * 64 + ((((lane >> 4) + t * 4) ^ (rb & 7)) * 8);
        }
    }

    for (int c0 = 0; c0 < K; c0 += 64) {
#pragma unroll
        for (int j = 0; j < 4; ++j) {
            const _Float16* ga = &A[(size_t)(m0 + srow[j]) * sa + c0 + scol[j]];
            const _Float16* gb = &Bw[(size_t)(n0 + srow[j]) * K + c0 + scol[j]];
            __builtin_amdgcn_global_load_lds((gas_t)(const void*)ga,
                                             (las_t)(void*)&Als[(w * 256 + j * 64) * 8], 16, 0, 0);
            __builtin_amdgcn_global_load_lds((gas_t)(const void*)gb,
                                             (las_t)(void*)&Bls[(w * 256 + j * 64) * 8], 16, 0, 0);
        }
        __syncthreads();
#pragma unroll
        for (int t = 0; t < 2; ++t) {
            half8v a[4], b[4];
#pragma unroll
            for (int i = 0; i < 4; ++i) {
                a[i] = *(const half8v*)&Als[aoff[i][t]];
                b[i] = *(const half8v*)&Bls[boff[i][t]];
            }
#pragma unroll
            for (int i = 0; i < 4; ++i)
#pragma unroll
                for (int j = 0; j < 4; ++j)
                    acc[i][j] = __builtin_amdgcn_mfma_f32_16x16x32_f16(a[i], b[j], acc[i][j], 0, 0, 0);
        }
        __syncthreads();
    }
#pragma unroll
    for (int i = 0; i < 4; ++i)
#pragma unroll
        for (int j = 0; j < 4; ++j)
#pragma unroll
            for (int e = 0; e < 4; ++e) {
                int row = m0 + wr + i * 16 + (lane >> 4) * 4 + e;
                int col = n0 + wc + j * 16 + (lane & 15);
                outp[(size_t)row * so + col] = (_Float16)acc[i][j][e];
            }
    if constexpr (STATS) {
        int slice = blockIdx.x & 63;
#pragma unroll
        for (int j = 0; j < 4; ++j) {
            float s = 0.f, q = 0.f;
#pragma unroll
            for (int i = 0; i < 4; ++i)
#pragma unroll
                for (int e = 0; e < 4; ++e) {
                    float v = acc[i][j][e];
                    s += v; q += v * v;
                }
            s += __shfl_xor(s, 16); s += __shfl_xor(s, 32);
            q += __shfl_xor(q, 16); q += __shfl_xor(q, 32);
            if ((lane >> 4) == 0) {
                int col = n0 + wc + j * 16 + lane;
                atomicAdd(&psum[slice * 1024 + col], s);
                atomicAdd(&psq[slice * 1024 + col], q);
            }
        }
        finalize_tail(psum, psq, gvec, bvec, 1.f / (B_ * N_), 1024,
                      (int)(gridDim.x * gridDim.y), scale, shift, cnt);
    }
}

// ---------------- layer-0: fused dense (C=3) + gather-reduce + BN stats + finalize ----------------
__global__ __launch_bounds__(256)
void k_gather0(const float* __restrict__ x, const float* __restrict__ w0,
               const int* __restrict__ nidx, const float* __restrict__ g,
               const float* __restrict__ bvec,
               _Float16* __restrict__ exth,
               float* __restrict__ psum, float* __restrict__ psq,
               float* __restrict__ scale, float* __restrict__ shift, int* __restrict__ cnt) {
    constexpr int O = 64, VPT = 8, P = 32;
    __shared__ float s_red[P * O];
    __shared__ float q_red[P * O];
    const int tid = threadIdx.x;
    const int pl = tid / VPT, v = tid % VPT;
    int bsw, local;
    swz_batch(blockIdx.x, bsw, local);               // grid 256: local in [0,32)
    const int bbase = bsw * N_;
    const int p = bbase + local * P + pl;
    // per-thread weights for channels v*8 .. v*8+7 (static-indexed -> registers)
    float wa[8][3], wd[8][3], sg[8];
#pragma unroll
    for (int e = 0; e < 8; ++e) {
        int o = v * 8 + e;
        float a0 = w0[o * 6], a1 = w0[o * 6 + 1], a2 = w0[o * 6 + 2];
        wa[e][0] = a0; wa[e][1] = a1; wa[e][2] = a2;
        wd[e][0] = w0[o * 6 + 3] - a0;
        wd[e][1] = w0[o * 6 + 4] - a1;
        wd[e][2] = w0[o * 6 + 5] - a2;
        sg[e] = (g[o] >= 0.f) ? 1.f : -1.f;
    }
    float mx[8], sm[8], sq[8];
#pragma unroll
    for (int e = 0; e < 8; ++e) { mx[e] = -3.4e38f; sm[e] = 0.f; sq[e] = 0.f; }
    const int* np = nidx + p * K_;
#pragma unroll 4
    for (int k = 0; k < K_; ++k) {
        int j = bbase + np[k];
        float x0 = x[j * 3], x1 = x[j * 3 + 1], x2 = x[j * 3 + 2];
#pragma unroll
        for (int e = 0; e < 8; ++e) {
            float f = wa[e][0] * x0 + wa[e][1] * x1 + wa[e][2] * x2;
            mx[e] = fmaxf(mx[e], f * sg[e]);
            sm[e] += f;
            sq[e] += f * f;
        }
    }
    float xp0 = x[p * 3], xp1 = x[p * 3 + 1], xp2 = x[p * 3 + 2];
    const float Kf = (float)K_;
    half8v exo;
#pragma unroll
    for (int e = 0; e < 8; ++e) {
        float zf = wd[e][0] * xp0 + wd[e][1] * xp1 + wd[e][2] * xp2;
        exo[e] = (_Float16)(sg[e] * mx[e] + zf);
        s_red[pl * O + v * 8 + e] = sm[e] + Kf * zf;
        q_red[pl * O + v * 8 + e] = sq[e] + 2.f * zf * sm[e] + Kf * zf * zf;
    }
    *(half8v*)&exth[(size_t)p * O + v * 8] = exo;
    __syncthreads();
    int slice = blockIdx.x & 63;
    for (int ch = tid; ch < O; ch += 256) {
        float s = 0.f, q = 0.f;
#pragma unroll
        for (int pp = 0; pp < P; ++pp) { s += s_red[pp * O + ch]; q += q_red[pp * O + ch]; }
        atomicAdd(&psum[slice * 1024 + ch], s);
        atomicAdd(&psq[slice * 1024 + ch], q);
    }
    finalize_tail(psum, psq, g, bvec, 1.f / (B_ * N_ * K_), O, (int)gridDim.x,
                  scale, shift, cnt);
}

// ---------------- gather-reduce + fused BN stats + finalize (batch-XCD-swizzled) ----------------
template<int O>
__global__ __launch_bounds__(256)
void k_gather(const _Float16* __restrict__ Z, const int* __restrict__ nidx,
              const float* __restrict__ g, const float* __restrict__ bvec,
              _Float16* __restrict__ exth,
              float* __restrict__ psum, float* __restrict__ psq,
              float* __restrict__ scale, float* __restrict__ shift, int* __restrict__ cnt) {
    constexpr int VPT = O / 8, P = 256 / VPT;
    __shared__ float s_red[P * O];
    __shared__ float q_red[P * O];
    const int tid = threadIdx.x;
    const int pl = tid / VPT, v = tid % VPT;
    int bsw, local;
    swz_batch(blockIdx.x, bsw, local);               // local in [0, 2048/P)
    const int bbase = bsw * N_;
    const int p = bbase + local * P + pl;
    float sg[8];
#pragma unroll
    for (int e = 0; e < 8; ++e) sg[e] = (g[v * 8 + e] >= 0.f) ? 1.f : -1.f;
    float mx[8], sm[8], sq[8];
#pragma unroll
    for (int e = 0; e < 8; ++e) { mx[e] = -3.4e38f; sm[e] = 0.f; sq[e] = 0.f; }
    const int* np = nidx + p * K_;
#pragma unroll 4
    for (int k = 0; k < K_; ++k) {
        int j = np[k];
        half8v z = *(const half8v*)&Z[(size_t)(bbase + j) * (2 * O) + v * 8];
#pragma unroll
        for (int e = 0; e < 8; ++e) {
            float f = (float)z[e];
            mx[e] = fmaxf(mx[e], f * sg[e]);
            sm[e] += f;
            sq[e] += f * f;
        }
    }
    half8v zd = *(const half8v*)&Z[(size_t)p * (2 * O) + O + v * 8];
    const float Kf = (float)K_;
    half8v exo;
#pragma unroll
    for (int e = 0; e < 8; ++e) {
        float zf = (float)zd[e];
        exo[e] = (_Float16)(sg[e] * mx[e] + zf);
        s_red[pl * O + v * 8 + e] = sm[e] + Kf * zf;
        q_red[pl * O + v * 8 + e] = sq[e] + 2.f * zf * sm[e] + Kf * zf * zf;
    }
    *(half8v*)&exth[(size_t)p * O + v * 8] = exo;
    __syncthreads();
    int slice = blockIdx.x & 63;
    for (int ch = tid; ch < O; ch += 256) {
        float s = 0.f, q = 0.f;
#pragma unroll
        for (int pp = 0; pp < P; ++pp) { s += s_red[pp * O + ch]; q += q_red[pp * O + ch]; }
        atomicAdd(&psum[slice * 1024 + ch], s);
        atomicAdd(&psq[slice * 1024 + ch], q);
    }
    finalize_tail(psum, psq, g, bvec, 1.f / (B_ * N_ * K_), O, (int)gridDim.x,
                  scale, shift, cnt);
}

// BN + lrelu on selected extremum (fp16 in) -> fp16 cat slice; batch-XCD-swizzled
template<int O>
__global__ void k_bn_apply(const _Float16* __restrict__ exth,
                           const float* __restrict__ scale, const float* __restrict__ shift,
                           _Float16* __restrict__ cath, int coff) {
    constexpr int PPB = 2048 / O;                    // points per block (256 thr x 8 elems)
    int bsw, local;
    swz_batch(blockIdx.x, bsw, local);
    const int pt_base = bsw * N_ + local * PPB;
    int tid = threadIdx.x;
    int pt = pt_base + (tid * 8) / O;
    int v8 = (tid * 8) & (O - 1);
    half8v hx = *(const half8v*)&exth[(size_t)pt * O + v8];
    half8v r;
#pragma unroll
    for (int e = 0; e < 8; ++e) {
        int o = v8 + e;
        float y = scale[o] * (float)hx[e] + shift[o];
        y = y > 0.f ? y : 0.2f * y;
        r[e] = (_Float16)y;
    }
    *(half8v*)&cath[(size_t)pt * 960 + coff + v8] = r;
}

// BN+lrelu on Y4 (B,N,1024 fp16), transposed store -> fo (B,1024,N f32), fused pool partials
__global__ void k_feats_out(const _Float16* __restrict__ Y4, const float* __restrict__ scale,
                            const float* __restrict__ shift, float* __restrict__ fo,
                            float* __restrict__ pmax, float* __restrict__ psumn) {
    __shared__ float tile[32][33];
    int tx = threadIdx.x, ty = threadIdx.y;      // (32,8)
    int b = blockIdx.z;
    int n0 = blockIdx.x * 32, c0 = blockIdx.y * 32;
#pragma unroll
    for (int i = 0; i < 4; ++i) {
        int n = n0 + ty + i * 8;
        int c = c0 + tx;
        float v = (float)Y4[((size_t)(b * N_ + n)) * 1024 + c];
        v = scale[c] * v + shift[c];
        v = v > 0.f ? v : 0.2f * v;
        tile[ty + i * 8][tx] = v;
    }
    __syncthreads();
#pragma unroll
    for (int i = 0; i < 4; ++i) {
        int c = c0 + ty + i * 8;
        int n = n0 + tx;
        float v2 = tile[tx][ty + i * 8];
        fo[((size_t)(b * 1024 + c)) * N_ + n] = v2;
        float mx = v2, s = v2;
#pragma unroll
        for (int d = 1; d < 32; d <<= 1) {
            mx = fmaxf(mx, __shfl_xor(mx, d));
            s += __shfl_xor(s, d);
        }
        if (tx == 0) {
            int bc = (b << 10) + c;
            pmax[(size_t)bc * 64 + blockIdx.x] = mx;
            psumn[(size_t)bc * 64 + blockIdx.x] = s;
        }
    }
}

// final pool: per (b,c) reduce 64 tile-partials -> z0 (B,2048) = [max | mean]
__global__ void k_pool2(const float* __restrict__ pmax, const float* __restrict__ psumn,
                        float* __restrict__ z0) {
    int bc = blockIdx.x * 4 + (threadIdx.x >> 6);
    int lane = threadIdx.x & 63;
    float mx = pmax[(size_t)bc * 64 + lane];
    float s  = psumn[(size_t)bc * 64 + lane];
#pragma unroll
    for (int d = 1; d < 64; d <<= 1) {
        mx = fmaxf(mx, __shfl_xor(mx, d));
        s += __shfl_xor(s, d);
    }
    if (lane == 0) {
        int b = bc >> 10, c = bc & 1023;
        z0[b * 2048 + c] = mx;
        z0[b * 2048 + 1024 + c] = s * (1.f / N_);
    }
}

// ---------------- FC: one wave per (batch, output) dot product; optional fused batch-BN+lrelu ----------------
// gg!=null: zout[b][o] = lrelu(bn_over_batch(zin@W^T + bias)) ; else plain +bias.
__global__ void k_fc(const float* __restrict__ zin, const float* __restrict__ W,
                     const float* __restrict__ bias,
                     const float* __restrict__ gg, const float* __restrict__ gb,
                     int C, int O, float* __restrict__ zout) {
    __shared__ float sh4[4];
    const int b = threadIdx.x >> 6;
    const int lane = threadIdx.x & 63;
    const int o = blockIdx.x;
    const float* wr = W + (size_t)o * C;
    const float* zr = zin + b * C;
    float s = 0.f;
    for (int c = lane * 4; c < C; c += 256) {
        const float4 wv = *(const float4*)&wr[c];
        const float4 zv = *(const float4*)&zr[c];
        s += wv.x * zv.x + wv.y * zv.y + wv.z * zv.z + wv.w * zv.w;
    }
    s += __shfl_xor(s, 1);
    s += __shfl_xor(s, 2);
    s += __shfl_xor(s, 4);
    s += __shfl_xor(s, 8);
    s += __shfl_xor(s, 16);
    s += __shfl_xor(s, 32);
    if (!gg) {
        if (lane == 0) zout[b * O + o] = s + (bias ? bias[o] : 0.f);
        return;
    }
    if (lane == 0) sh4[b] = s + (bias ? bias[o] : 0.f);
    __syncthreads();
    if (threadIdx.x == 0) {
        float v0 = sh4[0], v1 = sh4[1], v2 = sh4[2], v3 = sh4[3];
        float m = 0.25f * (v0 + v1 + v2 + v3);
        float d0 = v0 - m, d1 = v1 - m, d2 = v2 - m, d3 = v3 - m;
        float var = 0.25f * (d0 * d0 + d1 * d1 + d2 * d2 + d3 * d3);
        float sc = gg[o] * rsqrtf(var + EPSBN);
        float shv = gb[o];
        float r0 = sc * d0 + shv, r1 = sc * d1 + shv, r2 = sc * d2 + shv, r3 = sc * d3 + shv;
        zout[o]         = r0 > 0.f ? r0 : 0.2f * r0;
        zout[O + o]     = r1 > 0.f ? r1 : 0.2f * r1;
        zout[2 * O + o] = r2 > 0.f ? r2 : 0.2f * r2;
        zout[3 * O + o] = r3 > 0.f ? r3 : 0.2f * r3;
    }
}

// ---------------- launch ----------------

extern "C" void kernel_launch(void* const* d_in, const int* in_sizes, int n_in,
                              void* d_out, int out_size, void* d_ws, size_t ws_size,
                              hipStream_t stream) {
    const float* x    = (const float*)d_in[0];
    const int*   nidx = (const int*)d_in[1];
    const float* w[5]  = {(const float*)d_in[2], (const float*)d_in[5], (const float*)d_in[8],
                          (const float*)d_in[11], (const float*)d_in[14]};
    const float* g[5]  = {(const float*)d_in[3], (const float*)d_in[6], (const float*)d_in[9],
                          (const float*)d_in[12], (const float*)d_in[15]};
    const float* bb[5] = {(const float*)d_in[4], (const float*)d_in[7], (const float*)d_in[10],
                          (const float*)d_in[13], (const float*)d_in[16]};
    const float* lw1 = (const float*)d_in[17];
    const float* g6  = (const float*)d_in[18];
    const float* b6  = (const float*)d_in[19];
    const float* lw2 = (const float*)d_in[20];
    const float* lb2 = (const float*)d_in[21];
    const float* g7  = (const float*)d_in[22];
    const float* b7  = (const float*)d_in[23];
    const float* lw3 = (const float*)d_in[24];
    const float* lb3 = (const float*)d_in[25];

    float* out = (float*)d_out;
    float* fo  = out + 1024;              // feats (B,1024,N)

    uint8_t* base8 = (uint8_t*)d_ws;
    size_t off = 0;
    auto alloc = [&](size_t bytes) -> void* {
        void* r = base8 + off;
        off += (bytes + 255) & ~(size_t)255;
        return r;
    };
    _Float16* cath = (_Float16*)alloc((size_t)B_ * N_ * 960 * 2);   // 15.7 MB
    _Float16* Z    = (_Float16*)alloc((size_t)8192 * 1024 * 2);     // 16.8 MB
    _Float16* exth = (_Float16*)alloc((size_t)8192 * 512 * 2);      // 8.4 MB
    _Float16* Y4   = (_Float16*)alloc((size_t)8192 * 1024 * 2);     // 16.8 MB
    _Float16* W2h1 = (_Float16*)alloc((size_t)256 * 64 * 2);
    _Float16* W2h2 = (_Float16*)alloc((size_t)512 * 128 * 2);
    _Float16* W2h3 = (_Float16*)alloc((size_t)1024 * 256 * 2);
    _Float16* w4h  = (_Float16*)alloc((size_t)1024 * 960 * 2);
    float* psumall = (float*)alloc((size_t)5 * 131072 * 4);         // 2.6 MB, 5 regions
    int*   cnts    = (int*)alloc(256);                              // 5 block-completion counters
    float* pmax  = (float*)alloc((size_t)4096 * 64 * 4);            // 1 MB
    float* psumn = (float*)alloc((size_t)4096 * 64 * 4);            // 1 MB
    float* scalev= (float*)alloc(1024 * 4);
    float* shiftv= (float*)alloc(1024 * 4);
    float* z0    = (float*)alloc(8192 * 4);
    float* z1    = (float*)alloc(4096 * 4);
    float* z2    = (float*)alloc(2048 * 4);
    (void)ws_size; (void)in_sizes; (void)n_in; (void)out_size;

    auto psumR = [&](int r) { return psumall + (size_t)r * 131072; };
    auto psqR  = [&](int r) { return psumall + (size_t)r * 131072 + 65536; };

    // one upfront zero of all stat regions + counters, one fused weight-prep launch
    hipMemsetAsync(psumall, 0, (size_t)5 * 131072 * 4 + 256, stream);
    k_prep_all<<<(8192 + 32768 + 131072 + 983040 + 255) / 256, 256, 0, stream>>>(
        w[1], w[2], w[3], w[4], W2h1, W2h2, W2h3, w4h);

    // ---- layer 0 (C=3 -> O=64): fused dense + gather + stats + finalize ----
    k_gather0<<<256, 256, 0, stream>>>(x, w[0], nidx, g[0], bb[0], exth,
                                       psumR(0), psqR(0), scalev, shiftv, cnts + 0);
    k_bn_apply<64><<<256, 256, 0, stream>>>(exth, scalev, shiftv, cath, 0);

    // ---- layers 1-3: dense MFMA GEMM + fused gather(+finalize) ----
    struct LayerCfg { int coff_in, C, O, coff_out, li; const _Float16* Wh; };
    const LayerCfg L[3] = {
        { 0,   64,  128, 64,  1, W2h1 },
        { 64,  128, 256, 192, 2, W2h2 },
        { 192, 256, 512, 448, 3, W2h3 },
    };
    for (int i = 0; i < 3; ++i) {
        const LayerCfg& Lc = L[i];
        dim3 ggrid(64, (2 * Lc.O) / 128);
        k_gemm<false><<<ggrid, 256, 0, stream>>>(cath + Lc.coff_in, 960, Lc.Wh, Lc.C,
                                                 Z, 2 * Lc.O, nullptr, nullptr,
                                                 nullptr, nullptr, nullptr, nullptr, nullptr);
        if (Lc.O == 128) {
            k_gather<128><<<512, 256, 0, stream>>>(Z, nidx, g[Lc.li], bb[Lc.li], exth,
                                                   psumR(i + 1), psqR(i + 1),
                                                   scalev, shiftv, cnts + 8 * (i + 1));
            k_bn_apply<128><<<512, 256, 0, stream>>>(exth, scalev, shiftv, cath, Lc.coff_out);
        } else if (Lc.O == 256) {
            k_gather<256><<<1024, 256, 0, stream>>>(Z, nidx, g[Lc.li], bb[Lc.li], exth,
                                                    psumR(i + 1), psqR(i + 1),
                                                    scalev, shiftv, cnts + 8 * (i + 1));
            k_bn_apply<256><<<1024, 256, 0, stream>>>(exth, scalev, shiftv, cath, Lc.coff_out);
        } else {
            k_gather<512><<<2048, 256, 0, stream>>>(Z, nidx, g[Lc.li], bb[Lc.li], exth,
                                                    psumR(i + 1), psqR(i + 1),
                                                    scalev, shiftv, cnts + 8 * (i + 1));
            k_bn_apply<512><<<2048, 256, 0, stream>>>(exth, scalev, shiftv, cath, Lc.coff_out);
        }
    }

    // ---- feats = lrelu(bn(w4 @ cat)) with fused column stats + finalize ----
    k_gemm<true><<<dim3(64, 8), 256, 0, stream>>>(cath, 960, w4h, 960, Y4, 1024,
                                                  psumR(4), psqR(4), g[4], bb[4],
                                                  scalev, shiftv, cnts + 32);
    k_feats_out<<<dim3(64, 32, 4), dim3(32, 8), 0, stream>>>(Y4, scalev, shiftv, fo, pmax, psumn);
    k_pool2<<<1024, 256, 0, stream>>>(pmax, psumn, z0);

    // ---- FC head (BN fused into FC blocks) ----
    k_fc<<<1024, 256, 0, stream>>>(z0, lw1, nullptr, g6, b6, 2048, 1024, z1);
    k_fc<<<512, 256, 0, stream>>>(z1, lw2, lb2, g7, b7, 1024, 512, z2);
    k_fc<<<256, 256, 0, stream>>>(z2, lw3, lb3, nullptr, nullptr, 512, 256, out);
}

// Round 3
// 168.592 us; speedup vs baseline: 3.2789x; 1.2833x over previous
//
#include <hip/hip_runtime.h>
#include <cstddef>
#include <cstdint>

#define EPSBN 1e-5f
constexpr int B_ = 4, N_ = 2048, K_ = 20;

typedef __attribute__((ext_vector_type(8))) _Float16 half8v;
typedef __attribute__((ext_vector_type(4))) float f32x4;
typedef const __attribute__((address_space(1))) unsigned int* gas_t;
typedef __attribute__((address_space(3))) unsigned int* las_t;

// batch-XCD swizzle: block B -> (batch, local) with B&7 = XCD slot, batch b on slots {2b,2b+1}
__device__ __forceinline__ void swz_batch(int B, int& b, int& local) {
    b = (B & 7) >> 1;
    local = ((B >> 3) << 1) | (B & 1);
}

// ---------------- fused weight prep (layers 1-3 conv + w4 cast) ----------------

__device__ __forceinline__ void prep_conv(const float* __restrict__ W, _Float16* __restrict__ W2h,
                                          int O, int C, int i) {
    int o = i / C, c = i - o * C;
    float a = W[o * 2 * C + c];
    float d = W[o * 2 * C + C + c] - a;
    W2h[(size_t)o * C + c] = (_Float16)a;
    W2h[(size_t)(O + o) * C + c] = (_Float16)d;
}

__global__ void k_prep_all(const float* __restrict__ w1, const float* __restrict__ w2,
                           const float* __restrict__ w3, const float* __restrict__ w4,
                           _Float16* __restrict__ W2h1, _Float16* __restrict__ W2h2,
                           _Float16* __restrict__ W2h3, _Float16* __restrict__ w4h) {
    int i = blockIdx.x * 256 + threadIdx.x;
    if (i < 8192) { prep_conv(w1, W2h1, 128, 64, i); return; }
    i -= 8192;
    if (i < 32768) { prep_conv(w2, W2h2, 256, 128, i); return; }
    i -= 32768;
    if (i < 131072) { prep_conv(w3, W2h3, 512, 256, i); return; }
    i -= 131072;
    if (i < 983040) w4h[i] = (_Float16)w4[i];
}

// ---------------- generic MFMA GEMM: out(fp16) = A (8192 x K, stride sa) @ Bw^T ----------------
// 128x128 tile, 4 waves x (64x64), global_load_lds staging with XOR-swizzled LDS.
// 3 blocks/CU for latency hiding (32KB LDS each).
template<bool STATS>
__global__ __launch_bounds__(256, 3)
void k_gemm(const _Float16* __restrict__ A, int sa,
            const _Float16* __restrict__ Bw, int K,
            _Float16* __restrict__ outp, int so,
            float* __restrict__ psum, float* __restrict__ psq) {
    __shared__ __align__(16) _Float16 Als[128 * 64];
    __shared__ __align__(16) _Float16 Bls[128 * 64];
    const int tid = threadIdx.x, lane = tid & 63, w = tid >> 6;
    int bsw, lsw;
    swz_batch(blockIdx.x, bsw, lsw);                 // lsw in [0,16)
    const int m0 = (bsw * 16 + lsw) * 128;
    const int n0 = blockIdx.y * 128;
    const int wr = (w >> 1) * 64, wc = (w & 1) * 64;

    f32x4 acc[4][4];
#pragma unroll
    for (int i = 0; i < 4; ++i)
#pragma unroll
        for (int j = 0; j < 4; ++j) acc[i][j] = (f32x4){0.f, 0.f, 0.f, 0.f};

    int srow[4], scol[4];
#pragma unroll
    for (int j = 0; j < 4; ++j) {
        int idx = w * 256 + j * 64 + lane;
        srow[j] = idx >> 3;
        scol[j] = ((idx & 7) ^ (srow[j] & 7)) * 8;
    }
    int aoff[4][2], boff[4][2];
#pragma unroll
    for (int i = 0; i < 4; ++i) {
        int ra = wr + i * 16 + (lane & 15);
        int rb = wc + i * 16 + (lane & 15);
#pragma unroll
        for (int t = 0; t < 2; ++t) {
            aoff[i][t] = ra * 64 + ((((lane >> 4) + t * 4) ^ (ra & 7)) * 8);
            boff[i][t] = rb * 64 + ((((lane >> 4) + t * 4) ^ (rb & 7)) * 8);
        }
    }

    for (int c0 = 0; c0 < K; c0 += 64) {
#pragma unroll
        for (int j = 0; j < 4; ++j) {
            const _Float16* ga = &A[(size_t)(m0 + srow[j]) * sa + c0 + scol[j]];
            const _Float16* gb = &Bw[(size_t)(n0 + srow[j]) * K + c0 + scol[j]];
            __builtin_amdgcn_global_load_lds((gas_t)(const void*)ga,
                                             (las_t)(void*)&Als[(w * 256 + j * 64) * 8], 16, 0, 0);
            __builtin_amdgcn_global_load_lds((gas_t)(const void*)gb,
                                             (las_t)(void*)&Bls[(w * 256 + j * 64) * 8], 16, 0, 0);
        }
        __syncthreads();
#pragma unroll
        for (int t = 0; t < 2; ++t) {
            half8v a[4], b[4];
#pragma unroll
            for (int i = 0; i < 4; ++i) {
                a[i] = *(const half8v*)&Als[aoff[i][t]];
                b[i] = *(const half8v*)&Bls[boff[i][t]];
            }
#pragma unroll
            for (int i = 0; i < 4; ++i)
#pragma unroll
                for (int j = 0; j < 4; ++j)
                    acc[i][j] = __builtin_amdgcn_mfma_f32_16x16x32_f16(a[i], b[j], acc[i][j], 0, 0, 0);
        }
        __syncthreads();
    }
#pragma unroll
    for (int i = 0; i < 4; ++i)
#pragma unroll
        for (int j = 0; j < 4; ++j)
#pragma unroll
            for (int e = 0; e < 4; ++e) {
                int row = m0 + wr + i * 16 + (lane >> 4) * 4 + e;
                int col = n0 + wc + j * 16 + (lane & 15);
                outp[(size_t)row * so + col] = (_Float16)acc[i][j][e];
            }
    if constexpr (STATS) {
        int slice = blockIdx.x & 63;
#pragma unroll
        for (int j = 0; j < 4; ++j) {
            float s = 0.f, q = 0.f;
#pragma unroll
            for (int i = 0; i < 4; ++i)
#pragma unroll
                for (int e = 0; e < 4; ++e) {
                    float v = acc[i][j][e];
                    s += v; q += v * v;
                }
            s += __shfl_xor(s, 16); s += __shfl_xor(s, 32);
            q += __shfl_xor(q, 16); q += __shfl_xor(q, 32);
            if ((lane >> 4) == 0) {
                int col = n0 + wc + j * 16 + lane;
                atomicAdd(&psum[slice * 1024 + col], s);
                atomicAdd(&psq[slice * 1024 + col], q);
            }
        }
    }
}

// ---------------- layer-0: fused dense (C=3) + gather-reduce + BN stats ----------------
// replaces round-0's k_dense0 + k_gather<64>: recompute W*x in-register during the gather,
// eliminating the 2MB Z0 write+read and one dispatch. Stats finalized by k_finalize_sl.
__global__ __launch_bounds__(256)
void k_gather0(const float* __restrict__ x, const float* __restrict__ w0,
               const int* __restrict__ nidx, const float* __restrict__ g,
               _Float16* __restrict__ exth,
               float* __restrict__ psum, float* __restrict__ psq) {
    constexpr int O = 64, VPT = 8, P = 32;
    __shared__ float s_red[P * O];
    __shared__ float q_red[P * O];
    const int tid = threadIdx.x;
    const int pl = tid / VPT, v = tid % VPT;
    int bsw, local;
    swz_batch(blockIdx.x, bsw, local);               // grid 256: local in [0,32)
    const int bbase = bsw * N_;
    const int p = bbase + local * P + pl;
    // per-thread weights for channels v*8 .. v*8+7 (static-indexed -> registers)
    float wa[8][3], wd[8][3], sg[8];
#pragma unroll
    for (int e = 0; e < 8; ++e) {
        int o = v * 8 + e;
        float a0 = w0[o * 6], a1 = w0[o * 6 + 1], a2 = w0[o * 6 + 2];
        wa[e][0] = a0; wa[e][1] = a1; wa[e][2] = a2;
        wd[e][0] = w0[o * 6 + 3] - a0;
        wd[e][1] = w0[o * 6 + 4] - a1;
        wd[e][2] = w0[o * 6 + 5] - a2;
        sg[e] = (g[o] >= 0.f) ? 1.f : -1.f;
    }
    float mx[8], sm[8], sq[8];
#pragma unroll
    for (int e = 0; e < 8; ++e) { mx[e] = -3.4e38f; sm[e] = 0.f; sq[e] = 0.f; }
    const int* np = nidx + p * K_;
#pragma unroll 4
    for (int k = 0; k < K_; ++k) {
        int j = bbase + np[k];
        float x0 = x[j * 3], x1 = x[j * 3 + 1], x2 = x[j * 3 + 2];
#pragma unroll
        for (int e = 0; e < 8; ++e) {
            float f = wa[e][0] * x0 + wa[e][1] * x1 + wa[e][2] * x2;
            mx[e] = fmaxf(mx[e], f * sg[e]);
            sm[e] += f;
            sq[e] += f * f;
        }
    }
    float xp0 = x[p * 3], xp1 = x[p * 3 + 1], xp2 = x[p * 3 + 2];
    const float Kf = (float)K_;
    half8v exo;
#pragma unroll
    for (int e = 0; e < 8; ++e) {
        float zf = wd[e][0] * xp0 + wd[e][1] * xp1 + wd[e][2] * xp2;
        exo[e] = (_Float16)(sg[e] * mx[e] + zf);
        s_red[pl * O + v * 8 + e] = sm[e] + Kf * zf;
        q_red[pl * O + v * 8 + e] = sq[e] + 2.f * zf * sm[e] + Kf * zf * zf;
    }
    *(half8v*)&exth[(size_t)p * O + v * 8] = exo;
    __syncthreads();
    int slice = blockIdx.x & 63;
    for (int ch = tid; ch < O; ch += 256) {
        float s = 0.f, q = 0.f;
#pragma unroll
        for (int pp = 0; pp < P; ++pp) { s += s_red[pp * O + ch]; q += q_red[pp * O + ch]; }
        atomicAdd(&psum[slice * 1024 + ch], s);
        atomicAdd(&psq[slice * 1024 + ch], q);
    }
}

// ---------------- gather-reduce + fused BN stats (single extremum, batch-XCD-swizzled) ----------------
template<int O>
__global__ __launch_bounds__(256)
void k_gather(const _Float16* __restrict__ Z, const int* __restrict__ nidx,
              const float* __restrict__ g,
              _Float16* __restrict__ exth,
              float* __restrict__ psum, float* __restrict__ psq) {
    constexpr int VPT = O / 8, P = 256 / VPT;
    __shared__ float s_red[P * O];
    __shared__ float q_red[P * O];
    const int tid = threadIdx.x;
    const int pl = tid / VPT, v = tid % VPT;
    int bsw, local;
    swz_batch(blockIdx.x, bsw, local);               // local in [0, 2048/P)
    const int bbase = bsw * N_;
    const int p = bbase + local * P + pl;
    float sg[8];
#pragma unroll
    for (int e = 0; e < 8; ++e) sg[e] = (g[v * 8 + e] >= 0.f) ? 1.f : -1.f;
    float mx[8], sm[8], sq[8];
#pragma unroll
    for (int e = 0; e < 8; ++e) { mx[e] = -3.4e38f; sm[e] = 0.f; sq[e] = 0.f; }
    const int* np = nidx + p * K_;
#pragma unroll 4
    for (int k = 0; k < K_; ++k) {
        int j = np[k];
        half8v z = *(const half8v*)&Z[(size_t)(bbase + j) * (2 * O) + v * 8];
#pragma unroll
        for (int e = 0; e < 8; ++e) {
            float f = (float)z[e];
            mx[e] = fmaxf(mx[e], f * sg[e]);
            sm[e] += f;
            sq[e] += f * f;
        }
    }
    half8v zd = *(const half8v*)&Z[(size_t)p * (2 * O) + O + v * 8];
    const float Kf = (float)K_;
    half8v exo;
#pragma unroll
    for (int e = 0; e < 8; ++e) {
        float zf = (float)zd[e];
        exo[e] = (_Float16)(sg[e] * mx[e] + zf);
        s_red[pl * O + v * 8 + e] = sm[e] + Kf * zf;
        q_red[pl * O + v * 8 + e] = sq[e] + 2.f * zf * sm[e] + Kf * zf * zf;
    }
    *(half8v*)&exth[(size_t)p * O + v * 8] = exo;
    __syncthreads();
    int slice = blockIdx.x & 63;
    for (int ch = tid; ch < O; ch += 256) {
        float s = 0.f, q = 0.f;
#pragma unroll
        for (int pp = 0; pp < P; ++pp) { s += s_red[pp * O + ch]; q += q_red[pp * O + ch]; }
        atomicAdd(&psum[slice * 1024 + ch], s);
        atomicAdd(&psq[slice * 1024 + ch], q);
    }
}

// ---------------- finalize: sum 64 slices -> scale/shift ----------------
__global__ void k_finalize_sl(const float* __restrict__ psum, const float* __restrict__ psq,
                              const float* __restrict__ g, const float* __restrict__ b,
                              float cntInv, int O,
                              float* __restrict__ scale, float* __restrict__ shift) {
    int o = blockIdx.x * 256 + threadIdx.x;
    if (o >= O) return;
    float s = 0.f, q = 0.f;
    for (int i = 0; i < 64; ++i) { s += psum[i * 1024 + o]; q += psq[i * 1024 + o]; }
    float m = s * cntInv;
    float v = q * cntInv - m * m;
    float sc = g[o] * rsqrtf(fmaxf(v, 0.f) + EPSBN);
    scale[o] = sc;
    shift[o] = b[o] - m * sc;
}

// BN + lrelu on selected extremum (fp16 in) -> fp16 cat slice; batch-XCD-swizzled
template<int O>
__global__ void k_bn_apply(const _Float16* __restrict__ exth,
                           const float* __restrict__ scale, const float* __restrict__ shift,
                           _Float16* __restrict__ cath, int coff) {
    constexpr int PPB = 2048 / O;                    // points per block (256 thr x 8 elems)
    int bsw, local;
    swz_batch(blockIdx.x, bsw, local);
    const int pt_base = bsw * N_ + local * PPB;
    int tid = threadIdx.x;
    int pt = pt_base + (tid * 8) / O;
    int v8 = (tid * 8) & (O - 1);
    half8v hx = *(const half8v*)&exth[(size_t)pt * O + v8];
    half8v r;
#pragma unroll
    for (int e = 0; e < 8; ++e) {
        int o = v8 + e;
        float y = scale[o] * (float)hx[e] + shift[o];
        y = y > 0.f ? y : 0.2f * y;
        r[e] = (_Float16)y;
    }
    *(half8v*)&cath[(size_t)pt * 960 + coff + v8] = r;
}

// BN+lrelu on Y4 (B,N,1024 fp16), transposed store -> fo (B,1024,N f32), fused pool partials
__global__ void k_feats_out(const _Float16* __restrict__ Y4, const float* __restrict__ scale,
                            const float* __restrict__ shift, float* __restrict__ fo,
                            float* __restrict__ pmax, float* __restrict__ psumn) {
    __shared__ float tile[32][33];
    int tx = threadIdx.x, ty = threadIdx.y;      // (32,8)
    int b = blockIdx.z;
    int n0 = blockIdx.x * 32, c0 = blockIdx.y * 32;
#pragma unroll
    for (int i = 0; i < 4; ++i) {
        int n = n0 + ty + i * 8;
        int c = c0 + tx;
        float v = (float)Y4[((size_t)(b * N_ + n)) * 1024 + c];
        v = scale[c] * v + shift[c];
        v = v > 0.f ? v : 0.2f * v;
        tile[ty + i * 8][tx] = v;
    }
    __syncthreads();
#pragma unroll
    for (int i = 0; i < 4; ++i) {
        int c = c0 + ty + i * 8;
        int n = n0 + tx;
        float v2 = tile[tx][ty + i * 8];
        fo[((size_t)(b * 1024 + c)) * N_ + n] = v2;
        float mx = v2, s = v2;
#pragma unroll
        for (int d = 1; d < 32; d <<= 1) {
            mx = fmaxf(mx, __shfl_xor(mx, d));
            s += __shfl_xor(s, d);
        }
        if (tx == 0) {
            int bc = (b << 10) + c;
            pmax[(size_t)bc * 64 + blockIdx.x] = mx;
            psumn[(size_t)bc * 64 + blockIdx.x] = s;
        }
    }
}

// final pool: per (b,c) reduce 64 tile-partials -> z0 (B,2048) = [max | mean]
__global__ void k_pool2(const float* __restrict__ pmax, const float* __restrict__ psumn,
                        float* __restrict__ z0) {
    int bc = blockIdx.x * 4 + (threadIdx.x >> 6);
    int lane = threadIdx.x & 63;
    float mx = pmax[(size_t)bc * 64 + lane];
    float s  = psumn[(size_t)bc * 64 + lane];
#pragma unroll
    for (int d = 1; d < 64; d <<= 1) {
        mx = fmaxf(mx, __shfl_xor(mx, d));
        s += __shfl_xor(s, d);
    }
    if (lane == 0) {
        int b = bc >> 10, c = bc & 1023;
        z0[b * 2048 + c] = mx;
        z0[b * 2048 + 1024 + c] = s * (1.f / N_);
    }
}

// ---------------- FC: one wave per (batch, output) dot product; optional fused batch-BN+lrelu ----------------
// gg!=null: zout[b][o] = lrelu(bn_over_batch(zin@W^T + bias)) ; else plain +bias.
__global__ void k_fc(const float* __restrict__ zin, const float* __restrict__ W,
                     const float* __restrict__ bias,
                     const float* __restrict__ gg, const float* __restrict__ gb,
                     int C, int O, float* __restrict__ zout) {
    __shared__ float sh4[4];
    const int b = threadIdx.x >> 6;
    const int lane = threadIdx.x & 63;
    const int o = blockIdx.x;
    const float* wr = W + (size_t)o * C;
    const float* zr = zin + b * C;
    float s = 0.f;
    for (int c = lane * 4; c < C; c += 256) {
        const float4 wv = *(const float4*)&wr[c];
        const float4 zv = *(const float4*)&zr[c];
        s += wv.x * zv.x + wv.y * zv.y + wv.z * zv.z + wv.w * zv.w;
    }
    s += __shfl_xor(s, 1);
    s += __shfl_xor(s, 2);
    s += __shfl_xor(s, 4);
    s += __shfl_xor(s, 8);
    s += __shfl_xor(s, 16);
    s += __shfl_xor(s, 32);
    if (!gg) {
        if (lane == 0) zout[b * O + o] = s + (bias ? bias[o] : 0.f);
        return;
    }
    if (lane == 0) sh4[b] = s + (bias ? bias[o] : 0.f);
    __syncthreads();
    if (threadIdx.x == 0) {
        float v0 = sh4[0], v1 = sh4[1], v2 = sh4[2], v3 = sh4[3];
        float m = 0.25f * (v0 + v1 + v2 + v3);
        float d0 = v0 - m, d1 = v1 - m, d2 = v2 - m, d3 = v3 - m;
        float var = 0.25f * (d0 * d0 + d1 * d1 + d2 * d2 + d3 * d3);
        float sc = gg[o] * rsqrtf(var + EPSBN);
        float shv = gb[o];
        float r0 = sc * d0 + shv, r1 = sc * d1 + shv, r2 = sc * d2 + shv, r3 = sc * d3 + shv;
        zout[o]         = r0 > 0.f ? r0 : 0.2f * r0;
        zout[O + o]     = r1 > 0.f ? r1 : 0.2f * r1;
        zout[2 * O + o] = r2 > 0.f ? r2 : 0.2f * r2;
        zout[3 * O + o] = r3 > 0.f ? r3 : 0.2f * r3;
    }
}

// ---------------- launch ----------------

extern "C" void kernel_launch(void* const* d_in, const int* in_sizes, int n_in,
                              void* d_out, int out_size, void* d_ws, size_t ws_size,
                              hipStream_t stream) {
    const float* x    = (const float*)d_in[0];
    const int*   nidx = (const int*)d_in[1];
    const float* w[5]  = {(const float*)d_in[2], (const float*)d_in[5], (const float*)d_in[8],
                          (const float*)d_in[11], (const float*)d_in[14]};
    const float* g[5]  = {(const float*)d_in[3], (const float*)d_in[6], (const float*)d_in[9],
                          (const float*)d_in[12], (const float*)d_in[15]};
    const float* bb[5] = {(const float*)d_in[4], (const float*)d_in[7], (const float*)d_in[10],
                          (const float*)d_in[13], (const float*)d_in[16]};
    const float* lw1 = (const float*)d_in[17];
    const float* g6  = (const float*)d_in[18];
    const float* b6  = (const float*)d_in[19];
    const float* lw2 = (const float*)d_in[20];
    const float* lb2 = (const float*)d_in[21];
    const float* g7  = (const float*)d_in[22];
    const float* b7  = (const float*)d_in[23];
    const float* lw3 = (const float*)d_in[24];
    const float* lb3 = (const float*)d_in[25];

    float* out = (float*)d_out;
    float* fo  = out + 1024;              // feats (B,1024,N)

    uint8_t* base8 = (uint8_t*)d_ws;
    size_t off = 0;
    auto alloc = [&](size_t bytes) -> void* {
        void* r = base8 + off;
        off += (bytes + 255) & ~(size_t)255;
        return r;
    };
    _Float16* cath = (_Float16*)alloc((size_t)B_ * N_ * 960 * 2);   // 15.7 MB
    _Float16* Z    = (_Float16*)alloc((size_t)8192 * 1024 * 2);     // 16.8 MB
    _Float16* exth = (_Float16*)alloc((size_t)8192 * 512 * 2);      // 8.4 MB
    _Float16* Y4   = (_Float16*)alloc((size_t)8192 * 1024 * 2);     // 16.8 MB
    _Float16* W2h1 = (_Float16*)alloc((size_t)256 * 64 * 2);
    _Float16* W2h2 = (_Float16*)alloc((size_t)512 * 128 * 2);
    _Float16* W2h3 = (_Float16*)alloc((size_t)1024 * 256 * 2);
    _Float16* w4h  = (_Float16*)alloc((size_t)1024 * 960 * 2);
    float* psumall = (float*)alloc((size_t)5 * 131072 * 4);         // 2.6 MB, 5 regions
    float* pmax  = (float*)alloc((size_t)4096 * 64 * 4);            // 1 MB
    float* psumn = (float*)alloc((size_t)4096 * 64 * 4);            // 1 MB
    float* scalev= (float*)alloc(1024 * 4);
    float* shiftv= (float*)alloc(1024 * 4);
    float* z0    = (float*)alloc(8192 * 4);
    float* z1    = (float*)alloc(4096 * 4);
    float* z2    = (float*)alloc(2048 * 4);
    (void)ws_size; (void)in_sizes; (void)n_in; (void)out_size;

    auto psumR = [&](int r) { return psumall + (size_t)r * 131072; };
    auto psqR  = [&](int r) { return psumall + (size_t)r * 131072 + 65536; };

    // one upfront zero of all stat regions + one fused weight-prep launch
    hipMemsetAsync(psumall, 0, (size_t)5 * 131072 * 4, stream);
    k_prep_all<<<(8192 + 32768 + 131072 + 983040 + 255) / 256, 256, 0, stream>>>(
        w[1], w[2], w[3], w[4], W2h1, W2h2, W2h3, w4h);

    // ---- layer 0 (C=3 -> O=64): fused dense + gather (no Z0 round-trip) ----
    k_gather0<<<256, 256, 0, stream>>>(x, w[0], nidx, g[0], exth, psumR(0), psqR(0));
    k_finalize_sl<<<1, 256, 0, stream>>>(psumR(0), psqR(0), g[0], bb[0], 1.f / (B_ * N_ * K_),
                                         64, scalev, shiftv);
    k_bn_apply<64><<<256, 256, 0, stream>>>(exth, scalev, shiftv, cath, 0);

    // ---- layers 1-3: dense MFMA GEMM + fused gather ----
    struct LayerCfg { int coff_in, C, O, coff_out, li; const _Float16* Wh; };
    const LayerCfg L[3] = {
        { 0,   64,  128, 64,  1, W2h1 },
        { 64,  128, 256, 192, 2, W2h2 },
        { 192, 256, 512, 448, 3, W2h3 },
    };
    for (int i = 0; i < 3; ++i) {
        const LayerCfg& Lc = L[i];
        dim3 ggrid(64, (2 * Lc.O) / 128);
        k_gemm<false><<<ggrid, 256, 0, stream>>>(cath + Lc.coff_in, 960, Lc.Wh, Lc.C,
                                                 Z, 2 * Lc.O, nullptr, nullptr);
        if (Lc.O == 128) {
            k_gather<128><<<512, 256, 0, stream>>>(Z, nidx, g[Lc.li], exth, psumR(i + 1), psqR(i + 1));
            k_finalize_sl<<<1, 256, 0, stream>>>(psumR(i + 1), psqR(i + 1), g[Lc.li], bb[Lc.li],
                                                 1.f / (B_ * N_ * K_), 128, scalev, shiftv);
            k_bn_apply<128><<<512, 256, 0, stream>>>(exth, scalev, shiftv, cath, Lc.coff_out);
        } else if (Lc.O == 256) {
            k_gather<256><<<1024, 256, 0, stream>>>(Z, nidx, g[Lc.li], exth, psumR(i + 1), psqR(i + 1));
            k_finalize_sl<<<1, 256, 0, stream>>>(psumR(i + 1), psqR(i + 1), g[Lc.li], bb[Lc.li],
                                                 1.f / (B_ * N_ * K_), 256, scalev, shiftv);
            k_bn_apply<256><<<1024, 256, 0, stream>>>(exth, scalev, shiftv, cath, Lc.coff_out);
        } else {
            k_gather<512><<<2048, 256, 0, stream>>>(Z, nidx, g[Lc.li], exth, psumR(i + 1), psqR(i + 1));
            k_finalize_sl<<<2, 256, 0, stream>>>(psumR(i + 1), psqR(i + 1), g[Lc.li], bb[Lc.li],
                                                 1.f / (B_ * N_ * K_), 512, scalev, shiftv);
            k_bn_apply<512><<<2048, 256, 0, stream>>>(exth, scalev, shiftv, cath, Lc.coff_out);
        }
    }

    // ---- feats = lrelu(bn(w4 @ cat)) with fused column stats ----
    k_gemm<true><<<dim3(64, 8), 256, 0, stream>>>(cath, 960, w4h, 960, Y4, 1024, psumR(4), psqR(4));
    k_finalize_sl<<<4, 256, 0, stream>>>(psumR(4), psqR(4), g[4], bb[4], 1.f / (B_ * N_), 1024,
                                         scalev, shiftv);
    k_feats_out<<<dim3(64, 32, 4), dim3(32, 8), 0, stream>>>(Y4, scalev, shiftv, fo, pmax, psumn);
    k_pool2<<<1024, 256, 0, stream>>>(pmax, psumn, z0);

    // ---- FC head (BN fused into FC blocks) ----
    k_fc<<<1024, 256, 0, stream>>>(z0, lw1, nullptr, g6, b6, 2048, 1024, z1);
    k_fc<<<512, 256, 0, stream>>>(z1, lw2, lb2, g7, b7, 1024, 512, z2);
    k_fc<<<256, 256, 0, stream>>>(z2, lw3, lb3, nullptr, nullptr, 512, 256, out);
}